// Round 3
// baseline (222.388 us; speedup 1.0000x reference)
//
#include <hip/hip_runtime.h>

// YOLO layer: (64, 3*85, 44, 44) -> (64, 3*44*44, 85), fp32.
// Memory-bound (253 MB traffic, ~40 us roofline @ 6.3 TB/s). Prior best 223 us
// (~1.13 TB/s) -- pattern is coalesced, so the loss is structural:
//  (a) in+out = 253 MB ~= 256 MB L3: write-allocate stores thrash the input
//      out of Infinity Cache every iteration -> nontemporal stores keep the
//      126 MB input L3-resident across graph replays.
//  (b) scalar 4B stores -> float4 stores (16B/lane sweet spot, 4x fewer instrs).
//  (c) XCD-chunked block swizzle (5952 % 8 == 0, bijective): each XCD streams
//      ~24 contiguous (b,a) slabs -> sequential DRAM/L2 traffic per XCD.
// R1 fix: __builtin_nontemporal_store needs a clang ext_vector_type, not
// HIP_vector_type float4. R2: resubmit (GPU timeout, no data).

#define BSZ      64
#define NA       3
#define NC       80
#define GRID     44
#define SPATIAL  (GRID * GRID)       // 1936
#define CH       (5 + NC)            // 85
#define TILE     64
#define TILES_PER_BA ((SPATIAL + TILE - 1) / TILE)   // 31 (last tile: 16 valid)
#define LDSS     89                  // [s][c] row stride; (25s+c)%32 spreads banks
#define NF       (CH * (TILE / 4))   // 1360 float4 loads per block
#define NITER    ((NF + 255) / 256)  // 6
#define STRIDE_F 8.0f                // 352 / 44; cancels /STRIDE in scaled anchors
#define NXCD     8
#define NWG      (BSZ * NA * TILES_PER_BA)   // 5952 (divisible by 8)
#define CHUNK    (NWG / NXCD)                // 744

typedef float vfloat4 __attribute__((ext_vector_type(4)));

__device__ __forceinline__ float sigf(float x) {
    return 1.0f / (1.0f + __expf(-x));
}

__global__ __launch_bounds__(256, 4)
void yolo_kernel(const float* __restrict__ in, float* __restrict__ out) {
    __shared__ float tile[TILE * LDSS];   // 64*89*4 = 22,784 B -> ~6-7 blocks/CU

    // XCD-chunked swizzle: launch-id % 8 picks the XCD (round-robin dispatch);
    // give that XCD a contiguous chunk of work-items. Bijective since NWG%8==0.
    const int bid0 = blockIdx.x;
    const int bid  = (bid0 % NXCD) * CHUNK + bid0 / NXCD;

    const int t   = bid % TILES_PER_BA;
    const int ba  = bid / TILES_PER_BA;   // b*NA + a
    const int a   = ba % NA;

    const int s0    = t * TILE;
    const int valid = min(TILE, SPATIAL - s0);   // 64 or 16; always mult of 4

    const float aw = (a == 0) ? 10.0f : (a == 1) ? 16.0f : 33.0f;
    const float ah = (a == 0) ? 13.0f : (a == 1) ? 30.0f : 23.0f;

    const int tid = threadIdx.x;
    const float* inbase = in + (size_t)ba * CH * SPATIAL + s0;

    // ---- phase 1a: issue ALL global loads first (bytes in flight) ----
    float4 v[NITER];
    #pragma unroll
    for (int i = 0; i < NITER; ++i) {
        int f = tid + i * 256;            // f -> (channel c, spatial quad q)
        int c = f >> 4, q = f & 15;
        if (f < NF && q * 4 < valid)
            v[i] = *(const float4*)(inbase + (size_t)c * SPATIAL + q * 4);
    }

    // ---- phase 1b: transform + LDS transpose write ----
    #pragma unroll
    for (int i = 0; i < NITER; ++i) {
        int f = tid + i * 256;
        int c = f >> 4, q = f & 15;
        if (f >= NF || q * 4 >= valid) continue;
        float r[4] = {v[i].x, v[i].y, v[i].z, v[i].w};
        #pragma unroll
        for (int j = 0; j < 4; ++j) {
            int   sl = q * 4 + j;         // local spatial
            int   gs = s0 + sl;           // global spatial
            float x  = r[j];
            float o;
            if (c == 0)      o = (sigf(x) + (float)(gs % GRID)) * STRIDE_F;
            else if (c == 1) o = (sigf(x) + (float)(gs / GRID)) * STRIDE_F;
            else if (c == 2) o = __expf(x) * aw;
            else if (c == 3) o = __expf(x) * ah;
            else             o = sigf(x);  // conf + 80 classes
            tile[sl * LDSS + c] = o;
        }
    }
    __syncthreads();

    // ---- phase 2: float4 nontemporal stores (valid*85 floats/block) ----
    // Row wrap trick: element (s+1, c-85) sits at LDS offset base + j + 4,
    // because LDSS - CH == 4. So the j-th gathered float is
    // tile[base + j + (c+j >= CH ? 4 : 0)].
    const size_t obase = ((size_t)ba * SPATIAL + s0) * CH;  // 16B-aligned
    const int total = valid * CH;         // 5440 or 1360, both mult of 4
    for (int k4 = tid * 4; k4 < total; k4 += 1024) {
        int s = k4 / CH;                  // magic-mul
        int c = k4 - s * CH;
        int base = s * LDSS + c;
        vfloat4 w;
        w.x = tile[base];                            // c < 85 always
        w.y = tile[base + 1 + ((c + 1 >= CH) ? 4 : 0)];
        w.z = tile[base + 2 + ((c + 2 >= CH) ? 4 : 0)];
        w.w = tile[base + 3 + ((c + 3 >= CH) ? 4 : 0)];
        __builtin_nontemporal_store(w, (vfloat4*)(out + obase + k4));
    }
}

extern "C" void kernel_launch(void* const* d_in, const int* in_sizes, int n_in,
                              void* d_out, int out_size, void* d_ws, size_t ws_size,
                              hipStream_t stream) {
    const float* in = (const float*)d_in[0];
    float* out = (float*)d_out;
    yolo_kernel<<<NWG, 256, 0, stream>>>(in, out);
}